// Round 1
// baseline (2627.006 us; speedup 1.0000x reference)
//
#include <hip/hip_runtime.h>

#define N_NODES 100000
#define N_EDGES 1600000

// ---------------- CSR build ----------------

__global__ __launch_bounds__(256) void k_init(int* __restrict__ indeg,
                                              int* __restrict__ cursor, int n) {
    int i = blockIdx.x * blockDim.x + threadIdx.x;
    if (i < n) { indeg[i] = 0; cursor[i] = 0; }
}

__global__ __launch_bounds__(256) void k_indeg(const int* __restrict__ dst,
                                               int* __restrict__ indeg, int e) {
    int i = blockIdx.x * blockDim.x + threadIdx.x;
    if (i < e) atomicAdd(&indeg[dst[i]], 1);
}

__global__ __launch_bounds__(256) void k_dinv(const int* __restrict__ indeg,
                                              float* __restrict__ dinv, int n) {
    int i = blockIdx.x * blockDim.x + threadIdx.x;
    if (i < n) dinv[i] = rsqrtf((float)(indeg[i] + 1));  // +1 self-loop
}

// single-block exclusive scan over n (=100000) values, writes offsets[0..n]
__global__ __launch_bounds__(1024) void k_scan(const int* __restrict__ indeg,
                                               int* __restrict__ offsets, int n) {
    __shared__ int partial[1024];
    int tid = threadIdx.x;
    int chunk = (n + 1023) / 1024;
    int beg = tid * chunk;
    int end = beg + chunk; if (end > n) end = n; if (beg > n) beg = n;
    int sum = 0;
    for (int i = beg; i < end; ++i) sum += indeg[i];
    partial[tid] = sum;
    __syncthreads();
    // Hillis-Steele inclusive scan
    for (int off = 1; off < 1024; off <<= 1) {
        int v = (tid >= off) ? partial[tid - off] : 0;
        __syncthreads();
        partial[tid] += v;
        __syncthreads();
    }
    int run = (tid > 0) ? partial[tid - 1] : 0;  // exclusive prefix of this chunk
    for (int i = beg; i < end; ++i) { offsets[i] = run; run += indeg[i]; }
    if (tid == 1023) offsets[n] = run;  // total
}

__global__ __launch_bounds__(256) void k_scatter(const int* __restrict__ src,
                                                 const int* __restrict__ dst,
                                                 const float* __restrict__ dinv,
                                                 const int* __restrict__ offsets,
                                                 int* __restrict__ cursor,
                                                 int* __restrict__ csr_src,
                                                 float* __restrict__ csr_norm, int e) {
    int i = blockIdx.x * blockDim.x + threadIdx.x;
    if (i < e) {
        int d = dst[i], s = src[i];
        int pos = offsets[d] + atomicAdd(&cursor[d], 1);
        csr_src[pos] = s;
        csr_norm[pos] = dinv[s] * dinv[d];
    }
}

// ---------------- f32 GEMM: C[M,N] = A[M,K] * B[K,N] ----------------
// BM=64, BN=64, BK=16, 256 threads, 4x4 microtile per thread.

constexpr int BM = 64, BN = 64, BK = 16;

__global__ __launch_bounds__(256) void k_gemm(const float* __restrict__ A,
                                              const float* __restrict__ B,
                                              float* __restrict__ C,
                                              int M, int K, int N) {
    __shared__ float As[BK][BM];   // transposed A tile for contiguous reads
    __shared__ float Bs[BK][BN];
    const int row0 = blockIdx.x * BM;
    const int col0 = blockIdx.y * BN;
    const int tid = threadIdx.x;
    const int tx = tid & 15;   // 0..15 -> 4 output cols each
    const int ty = tid >> 4;   // 0..15 -> 4 output rows each
    float acc[4][4] = {};

    for (int k0 = 0; k0 < K; k0 += BK) {
        // stage A: 64 rows x 16 k, float4 per thread, store transposed
        {
            int r = tid >> 2;            // 0..63
            int c = (tid & 3) << 2;      // 0,4,8,12
            int grow = row0 + r;
            float4 va = (grow < M) ? *(const float4*)(A + (size_t)grow * K + k0 + c)
                                   : make_float4(0.f, 0.f, 0.f, 0.f);
            As[c + 0][r] = va.x; As[c + 1][r] = va.y;
            As[c + 2][r] = va.z; As[c + 3][r] = va.w;
        }
        // stage B: 16 k x 64 cols, float4 per thread
        {
            int rb = tid >> 4;           // 0..15
            int cb = (tid & 15) << 2;    // 0..60
            *(float4*)&Bs[rb][cb] = *(const float4*)(B + (size_t)(k0 + rb) * N + col0 + cb);
        }
        __syncthreads();
#pragma unroll
        for (int kk = 0; kk < BK; ++kk) {
            float4 a = *(const float4*)&As[kk][ty << 2];
            float4 b = *(const float4*)&Bs[kk][tx << 2];
            float av[4] = {a.x, a.y, a.z, a.w};
            float bv[4] = {b.x, b.y, b.z, b.w};
#pragma unroll
            for (int i = 0; i < 4; ++i)
#pragma unroll
                for (int j = 0; j < 4; ++j) acc[i][j] += av[i] * bv[j];
        }
        __syncthreads();
    }
#pragma unroll
    for (int i = 0; i < 4; ++i) {
        int grow = row0 + (ty << 2) + i;
        if (grow < M) {
            float4 o = make_float4(acc[i][0], acc[i][1], acc[i][2], acc[i][3]);
            *(float4*)(C + (size_t)grow * N + col0 + (tx << 2)) = o;
        }
    }
}

// ---------------- aggregation: out = relu(Anorm * H + b) ----------------
// one wave per node; VEC floats per lane (F = 64*VEC)

template <int VEC>
__global__ __launch_bounds__(256) void k_aggregate(const float* __restrict__ H,
                                                   const int* __restrict__ offsets,
                                                   const int* __restrict__ csr_src,
                                                   const float* __restrict__ csr_norm,
                                                   const float* __restrict__ dinv,
                                                   const float* __restrict__ bias,
                                                   float* __restrict__ out, int n) {
    constexpr int F = 64 * VEC;
    const int wid = (blockIdx.x * blockDim.x + threadIdx.x) >> 6;
    const int lane = threadIdx.x & 63;
    if (wid >= n) return;

    float acc[VEC];
#pragma unroll
    for (int v = 0; v < VEC; ++v) acc[v] = 0.f;

    const int beg = offsets[wid], end = offsets[wid + 1];
    for (int e = beg; e < end; ++e) {
        int s = csr_src[e];
        float nrm = csr_norm[e];
        const float* hrow = H + (size_t)s * F;
        if (VEC == 4) {
            float4 v = *(const float4*)(hrow + (lane << 2));
            acc[0] += v.x * nrm; acc[1] += v.y * nrm;
            acc[2] += v.z * nrm; acc[3] += v.w * nrm;
        } else {
            acc[0] += hrow[lane] * nrm;
        }
    }
    // self-loop
    float dv = dinv[wid];
    float sw = dv * dv;
    const float* hs = H + (size_t)wid * F;
    if (VEC == 4) {
        float4 v = *(const float4*)(hs + (lane << 2));
        acc[0] += v.x * sw; acc[1] += v.y * sw;
        acc[2] += v.z * sw; acc[3] += v.w * sw;
        float4 b = *(const float4*)(bias + (lane << 2));
        float4 o = make_float4(fmaxf(acc[0] + b.x, 0.f), fmaxf(acc[1] + b.y, 0.f),
                               fmaxf(acc[2] + b.z, 0.f), fmaxf(acc[3] + b.w, 0.f));
        *(float4*)(out + (size_t)wid * F + (lane << 2)) = o;
    } else {
        float o = fmaxf(acc[0] + hs[lane] * sw + bias[lane], 0.f);
        out[(size_t)wid * F + lane] = o;
    }
}

// ---------------- launch ----------------

extern "C" void kernel_launch(void* const* d_in, const int* in_sizes, int n_in,
                              void* d_out, int out_size, void* d_ws, size_t ws_size,
                              hipStream_t stream) {
    const float* x      = (const float*)d_in[0];
    const float* W_enc  = (const float*)d_in[1];
    const float* b_enc  = (const float*)d_in[2];
    const float* W_conv = (const float*)d_in[3];
    const float* b_conv = (const float*)d_in[4];
    const float* W_dec  = (const float*)d_in[5];
    const float* b_dec  = (const float*)d_in[6];
    const int*   ei     = (const int*)d_in[7];

    const int N = N_NODES;
    const int E = N_EDGES;
    const int*  src = ei;
    const int*  dst = ei + E;

    // carve workspace (256B aligned)
    size_t off = 0;
    auto carve = [&](size_t bytes) -> void* {
        void* p = (char*)d_ws + off;
        off = (off + bytes + 255) & ~(size_t)255;
        return p;
    };
    float* bufA     = (float*)carve((size_t)N * 256 * sizeof(float));
    float* bufB     = (float*)carve((size_t)N * 256 * sizeof(float));
    int*   indeg    = (int*)carve((size_t)N * sizeof(int));
    int*   cursor   = (int*)carve((size_t)N * sizeof(int));
    float* dinv     = (float*)carve((size_t)N * sizeof(float));
    int*   offsets  = (int*)carve((size_t)(N + 1) * sizeof(int));
    int*   csr_src  = (int*)carve((size_t)E * sizeof(int));
    float* csr_norm = (float*)carve((size_t)E * sizeof(float));
    (void)ws_size;

    // --- CSR build ---
    k_init<<<(N + 255) / 256, 256, 0, stream>>>(indeg, cursor, N);
    k_indeg<<<(E + 255) / 256, 256, 0, stream>>>(dst, indeg, E);
    k_dinv<<<(N + 255) / 256, 256, 0, stream>>>(indeg, dinv, N);
    k_scan<<<1, 1024, 0, stream>>>(indeg, offsets, N);
    k_scatter<<<(E + 255) / 256, 256, 0, stream>>>(src, dst, dinv, offsets, cursor,
                                                   csr_src, csr_norm, E);

    const int gm = (N + BM - 1) / BM;  // 1563
    dim3 gemm_grid_256(gm, 256 / BN);
    dim3 gemm_grid_64(gm, 64 / BN);
    const int agg_blocks = (N * 64 + 255) / 256;  // 4 waves/block, 1 node/wave

    // --- encoder: relu(Anorm*(x@W_enc)+b_enc) -> bufA ---
    k_gemm<<<gemm_grid_256, 256, 0, stream>>>(x, W_enc, bufB, N, 256, 256);
    k_aggregate<4><<<agg_blocks, 256, 0, stream>>>(bufB, offsets, csr_src, csr_norm,
                                                   dinv, b_enc, bufA, N);
    // --- 4 conv layers ---
    for (int l = 0; l < 4; ++l) {
        k_gemm<<<gemm_grid_256, 256, 0, stream>>>(bufA, W_conv, bufB, N, 256, 256);
        k_aggregate<4><<<agg_blocks, 256, 0, stream>>>(bufB, offsets, csr_src, csr_norm,
                                                       dinv, b_conv, bufA, N);
    }
    // --- decoder: relu(Anorm*(X@W_dec)+b_dec) -> d_out ---
    k_gemm<<<gemm_grid_64, 256, 0, stream>>>(bufA, W_dec, bufB, N, 256, 64);
    k_aggregate<1><<<agg_blocks, 256, 0, stream>>>(bufB, offsets, csr_src, csr_norm,
                                                   dinv, b_dec, (float*)d_out, N);
}

// Round 2
// 1944.016 us; speedup vs baseline: 1.3513x; 1.3513x over previous
//
#include <hip/hip_runtime.h>

#define N_NODES 100000
#define N_EDGES 1600000

typedef unsigned short ushort8 __attribute__((ext_vector_type(8)));

__device__ inline unsigned short f2bf(float f) {
    unsigned u = __float_as_uint(f);
    unsigned r = (u + 0x7fffu + ((u >> 16) & 1u)) >> 16;  // RNE
    return (unsigned short)r;
}
__device__ inline float bf2f(unsigned short h) {
    return __uint_as_float(((unsigned)h) << 16);
}

// ---------------- CSR build ----------------

__global__ __launch_bounds__(256) void k_init(int* __restrict__ indeg,
                                              int* __restrict__ cursor, int n) {
    int i = blockIdx.x * blockDim.x + threadIdx.x;
    if (i < n) { indeg[i] = 0; cursor[i] = 0; }
}

__global__ __launch_bounds__(256) void k_indeg(const int* __restrict__ dst,
                                               int* __restrict__ indeg, int e) {
    int i = blockIdx.x * blockDim.x + threadIdx.x;
    if (i < e) atomicAdd(&indeg[dst[i]], 1);
}

__global__ __launch_bounds__(256) void k_dinv(const int* __restrict__ indeg,
                                              float* __restrict__ dinv, int n) {
    int i = blockIdx.x * blockDim.x + threadIdx.x;
    if (i < n) dinv[i] = rsqrtf((float)(indeg[i] + 1));  // +1 self-loop
}

__global__ __launch_bounds__(1024) void k_scan(const int* __restrict__ indeg,
                                               int* __restrict__ offsets, int n) {
    __shared__ int partial[1024];
    int tid = threadIdx.x;
    int chunk = (n + 1023) / 1024;
    int beg = tid * chunk;
    int end = beg + chunk; if (end > n) end = n; if (beg > n) beg = n;
    int sum = 0;
    for (int i = beg; i < end; ++i) sum += indeg[i];
    partial[tid] = sum;
    __syncthreads();
    for (int off = 1; off < 1024; off <<= 1) {
        int v = (tid >= off) ? partial[tid - off] : 0;
        __syncthreads();
        partial[tid] += v;
        __syncthreads();
    }
    int run = (tid > 0) ? partial[tid - 1] : 0;
    for (int i = beg; i < end; ++i) { offsets[i] = run; run += indeg[i]; }
    if (tid == 1023) offsets[n] = run;
}

__global__ __launch_bounds__(256) void k_scatter(const int* __restrict__ src,
                                                 const int* __restrict__ dst,
                                                 const float* __restrict__ dinv,
                                                 const int* __restrict__ offsets,
                                                 int* __restrict__ cursor,
                                                 int* __restrict__ csr_src,
                                                 float* __restrict__ csr_norm, int e) {
    int i = blockIdx.x * blockDim.x + threadIdx.x;
    if (i < e) {
        int d = dst[i], s = src[i];
        int pos = offsets[d] + atomicAdd(&cursor[d], 1);
        csr_src[pos] = s;
        csr_norm[pos] = dinv[s] * dinv[d];
    }
}

// ---------------- f32 GEMM 128x128, bf16 output ----------------
// C[M,N] = A[M,K]*B[K,N]; requires N % 128 == 0. 256 thr, 8x8 microtile.

constexpr int GBM = 128, GBN = 128, GBK = 16;

__global__ __launch_bounds__(256) void k_gemm128(const float* __restrict__ A,
                                                 const float* __restrict__ B,
                                                 unsigned short* __restrict__ C,
                                                 int M, int K, int N) {
    __shared__ float As[GBK][GBM];   // transposed A tile
    __shared__ float Bs[GBK][GBN];
    const int row0 = blockIdx.x * GBM;
    const int col0 = blockIdx.y * GBN;
    const int tid = threadIdx.x;
    const int tx = tid & 15;   // col group: 8 cols
    const int ty = tid >> 4;   // row group: 8 rows
    float acc[8][8] = {};

    for (int k0 = 0; k0 < K; k0 += GBK) {
        // stage A: 128 rows x 16 k; thread: row=tid>>1, c=(tid&1)*8 (two float4)
        {
            int r = tid >> 1;
            int c = (tid & 1) << 3;
            int grow = row0 + r;
            float4 v0 = make_float4(0.f, 0.f, 0.f, 0.f), v1 = v0;
            if (grow < M) {
                const float* ap = A + (size_t)grow * K + k0 + c;
                v0 = *(const float4*)ap;
                v1 = *(const float4*)(ap + 4);
            }
            As[c + 0][r] = v0.x; As[c + 1][r] = v0.y;
            As[c + 2][r] = v0.z; As[c + 3][r] = v0.w;
            As[c + 4][r] = v1.x; As[c + 5][r] = v1.y;
            As[c + 6][r] = v1.z; As[c + 7][r] = v1.w;
        }
        // stage B: 16 k x 128 cols; thread: rb=tid>>4, cb=(tid&15)*8
        {
            int rb = tid >> 4;
            int cb = (tid & 15) << 3;
            const float* bp = B + (size_t)(k0 + rb) * N + col0 + cb;
            *(float4*)&Bs[rb][cb] = *(const float4*)bp;
            *(float4*)&Bs[rb][cb + 4] = *(const float4*)(bp + 4);
        }
        __syncthreads();
#pragma unroll
        for (int kk = 0; kk < GBK; ++kk) {
            float a[8], b[8];
            *(float4*)&a[0] = *(const float4*)&As[kk][ty << 3];
            *(float4*)&a[4] = *(const float4*)&As[kk][(ty << 3) + 4];
            *(float4*)&b[0] = *(const float4*)&Bs[kk][tx << 3];
            *(float4*)&b[4] = *(const float4*)&Bs[kk][(tx << 3) + 4];
#pragma unroll
            for (int i = 0; i < 8; ++i)
#pragma unroll
                for (int j = 0; j < 8; ++j) acc[i][j] += a[i] * b[j];
        }
        __syncthreads();
    }
#pragma unroll
    for (int i = 0; i < 8; ++i) {
        int grow = row0 + (ty << 3) + i;
        if (grow < M) {
            ushort8 o;
#pragma unroll
            for (int j = 0; j < 8; ++j) o[j] = f2bf(acc[i][j]);
            *(ushort8*)(C + (size_t)grow * N + col0 + (tx << 3)) = o;
        }
    }
}

// ---------------- f32 GEMM 64x64 (for N=64 decoder), bf16 output ----------------

constexpr int BM = 64, BN = 64, BK = 16;

__global__ __launch_bounds__(256) void k_gemm64(const float* __restrict__ A,
                                                const float* __restrict__ B,
                                                unsigned short* __restrict__ C,
                                                int M, int K, int N) {
    __shared__ float As[BK][BM];
    __shared__ float Bs[BK][BN];
    const int row0 = blockIdx.x * BM;
    const int col0 = blockIdx.y * BN;
    const int tid = threadIdx.x;
    const int tx = tid & 15;
    const int ty = tid >> 4;
    float acc[4][4] = {};

    for (int k0 = 0; k0 < K; k0 += BK) {
        {
            int r = tid >> 2;
            int c = (tid & 3) << 2;
            int grow = row0 + r;
            float4 va = (grow < M) ? *(const float4*)(A + (size_t)grow * K + k0 + c)
                                   : make_float4(0.f, 0.f, 0.f, 0.f);
            As[c + 0][r] = va.x; As[c + 1][r] = va.y;
            As[c + 2][r] = va.z; As[c + 3][r] = va.w;
        }
        {
            int rb = tid >> 4;
            int cb = (tid & 15) << 2;
            *(float4*)&Bs[rb][cb] = *(const float4*)(B + (size_t)(k0 + rb) * N + col0 + cb);
        }
        __syncthreads();
#pragma unroll
        for (int kk = 0; kk < BK; ++kk) {
            float4 a = *(const float4*)&As[kk][ty << 2];
            float4 b = *(const float4*)&Bs[kk][tx << 2];
            float av[4] = {a.x, a.y, a.z, a.w};
            float bv[4] = {b.x, b.y, b.z, b.w};
#pragma unroll
            for (int i = 0; i < 4; ++i)
#pragma unroll
                for (int j = 0; j < 4; ++j) acc[i][j] += av[i] * bv[j];
        }
        __syncthreads();
    }
#pragma unroll
    for (int i = 0; i < 4; ++i) {
        int grow = row0 + (ty << 2) + i;
        if (grow < M) {
            ushort4 o;
            o.x = f2bf(acc[i][0]); o.y = f2bf(acc[i][1]);
            o.z = f2bf(acc[i][2]); o.w = f2bf(acc[i][3]);
            *(ushort4*)(C + (size_t)grow * N + col0 + (tx << 2)) = o;
        }
    }
}

// ---------------- aggregation: out = relu(Anorm * H + b), H in bf16 ----------------
// one wave per node; VEC bf16 per lane (F = 64*VEC)

template <int VEC>
__global__ __launch_bounds__(256) void k_aggregate(const unsigned short* __restrict__ H,
                                                   const int* __restrict__ offsets,
                                                   const int* __restrict__ csr_src,
                                                   const float* __restrict__ csr_norm,
                                                   const float* __restrict__ dinv,
                                                   const float* __restrict__ bias,
                                                   float* __restrict__ out, int n) {
    constexpr int F = 64 * VEC;
    const int wid = (blockIdx.x * blockDim.x + threadIdx.x) >> 6;
    const int lane = threadIdx.x & 63;
    if (wid >= n) return;

    float acc[VEC];
#pragma unroll
    for (int v = 0; v < VEC; ++v) acc[v] = 0.f;

    const int beg = offsets[wid], end = offsets[wid + 1];
    int e = beg;
    for (; e + 1 < end; e += 2) {
        int s0 = csr_src[e], s1 = csr_src[e + 1];
        float n0 = csr_norm[e], n1 = csr_norm[e + 1];
        if (VEC == 4) {
            ushort4 v0 = *(const ushort4*)(H + (size_t)s0 * F + (lane << 2));
            ushort4 v1 = *(const ushort4*)(H + (size_t)s1 * F + (lane << 2));
            acc[0] += bf2f(v0.x) * n0; acc[1] += bf2f(v0.y) * n0;
            acc[2] += bf2f(v0.z) * n0; acc[3] += bf2f(v0.w) * n0;
            acc[0] += bf2f(v1.x) * n1; acc[1] += bf2f(v1.y) * n1;
            acc[2] += bf2f(v1.z) * n1; acc[3] += bf2f(v1.w) * n1;
        } else {
            acc[0] += bf2f(H[(size_t)s0 * F + lane]) * n0;
            acc[0] += bf2f(H[(size_t)s1 * F + lane]) * n1;
        }
    }
    for (; e < end; ++e) {
        int s = csr_src[e];
        float nrm = csr_norm[e];
        if (VEC == 4) {
            ushort4 v = *(const ushort4*)(H + (size_t)s * F + (lane << 2));
            acc[0] += bf2f(v.x) * nrm; acc[1] += bf2f(v.y) * nrm;
            acc[2] += bf2f(v.z) * nrm; acc[3] += bf2f(v.w) * nrm;
        } else {
            acc[0] += bf2f(H[(size_t)s * F + lane]) * nrm;
        }
    }
    // self-loop
    float dv = dinv[wid];
    float sw = dv * dv;
    if (VEC == 4) {
        ushort4 v = *(const ushort4*)(H + (size_t)wid * F + (lane << 2));
        float4 b = *(const float4*)(bias + (lane << 2));
        float4 o = make_float4(fmaxf(acc[0] + bf2f(v.x) * sw + b.x, 0.f),
                               fmaxf(acc[1] + bf2f(v.y) * sw + b.y, 0.f),
                               fmaxf(acc[2] + bf2f(v.z) * sw + b.z, 0.f),
                               fmaxf(acc[3] + bf2f(v.w) * sw + b.w, 0.f));
        *(float4*)(out + (size_t)wid * F + (lane << 2)) = o;
    } else {
        float o = fmaxf(acc[0] + bf2f(H[(size_t)wid * F + lane]) * sw + bias[lane], 0.f);
        out[(size_t)wid * F + lane] = o;
    }
}

// ---------------- launch ----------------

extern "C" void kernel_launch(void* const* d_in, const int* in_sizes, int n_in,
                              void* d_out, int out_size, void* d_ws, size_t ws_size,
                              hipStream_t stream) {
    const float* x      = (const float*)d_in[0];
    const float* W_enc  = (const float*)d_in[1];
    const float* b_enc  = (const float*)d_in[2];
    const float* W_conv = (const float*)d_in[3];
    const float* b_conv = (const float*)d_in[4];
    const float* W_dec  = (const float*)d_in[5];
    const float* b_dec  = (const float*)d_in[6];
    const int*   ei     = (const int*)d_in[7];

    const int N = N_NODES;
    const int E = N_EDGES;
    const int* src = ei;
    const int* dst = ei + E;

    size_t off = 0;
    auto carve = [&](size_t bytes) -> void* {
        void* p = (char*)d_ws + off;
        off = (off + bytes + 255) & ~(size_t)255;
        return p;
    };
    float*          bufA     = (float*)carve((size_t)N * 256 * sizeof(float));
    unsigned short* bufH     = (unsigned short*)carve((size_t)N * 256 * sizeof(unsigned short));
    int*            indeg    = (int*)carve((size_t)N * sizeof(int));
    int*            cursor   = (int*)carve((size_t)N * sizeof(int));
    float*          dinv     = (float*)carve((size_t)N * sizeof(float));
    int*            offsets  = (int*)carve((size_t)(N + 1) * sizeof(int));
    int*            csr_src  = (int*)carve((size_t)E * sizeof(int));
    float*          csr_norm = (float*)carve((size_t)E * sizeof(float));
    (void)ws_size;

    // --- CSR build ---
    k_init<<<(N + 255) / 256, 256, 0, stream>>>(indeg, cursor, N);
    k_indeg<<<(E + 255) / 256, 256, 0, stream>>>(dst, indeg, E);
    k_dinv<<<(N + 255) / 256, 256, 0, stream>>>(indeg, dinv, N);
    k_scan<<<1, 1024, 0, stream>>>(indeg, offsets, N);
    k_scatter<<<(E + 255) / 256, 256, 0, stream>>>(src, dst, dinv, offsets, cursor,
                                                   csr_src, csr_norm, E);

    dim3 g128((N + GBM - 1) / GBM, 256 / GBN);   // 782 x 2
    dim3 g64((N + BM - 1) / BM, 1);              // decoder: N=64 -> 1563 x 1
    const int agg_blocks = (N * 64 + 255) / 256;

    // --- encoder ---
    k_gemm128<<<g128, 256, 0, stream>>>(x, W_enc, bufH, N, 256, 256);
    k_aggregate<4><<<agg_blocks, 256, 0, stream>>>(bufH, offsets, csr_src, csr_norm,
                                                   dinv, b_enc, bufA, N);
    // --- 4 conv layers ---
    for (int l = 0; l < 4; ++l) {
        k_gemm128<<<g128, 256, 0, stream>>>(bufA, W_conv, bufH, N, 256, 256);
        k_aggregate<4><<<agg_blocks, 256, 0, stream>>>(bufH, offsets, csr_src, csr_norm,
                                                       dinv, b_conv, bufA, N);
    }
    // --- decoder ---
    k_gemm64<<<g64, 256, 0, stream>>>(bufA, W_dec, bufH, N, 256, 64);
    k_aggregate<1><<<agg_blocks, 256, 0, stream>>>(bufH, offsets, csr_src, csr_norm,
                                                   dinv, b_dec, (float*)d_out, N);
}

// Round 3
// 1191.794 us; speedup vs baseline: 2.2042x; 1.6312x over previous
//
#include <hip/hip_runtime.h>

#define N_NODES 100000
#define N_EDGES 1600000
#define MPAD    100096   // 782 * 128

using short8 = __attribute__((ext_vector_type(8))) short;
using f32x4  = __attribute__((ext_vector_type(4))) float;

__device__ inline unsigned short f2bf(float f) {
    unsigned u = __float_as_uint(f);
    unsigned r = (u + 0x7fffu + ((u >> 16) & 1u)) >> 16;  // RNE
    return (unsigned short)r;
}
__device__ inline float bf2f(unsigned short h) {
    return __uint_as_float(((unsigned)h) << 16);
}

// ---------------- CSR build ----------------

__global__ __launch_bounds__(256) void k_init(int* __restrict__ indeg,
                                              int* __restrict__ cursor, int n) {
    int i = blockIdx.x * blockDim.x + threadIdx.x;
    if (i < n) { indeg[i] = 0; cursor[i] = 0; }
}

__global__ __launch_bounds__(256) void k_indeg(const int* __restrict__ dst,
                                               int* __restrict__ indeg, int e) {
    int i = blockIdx.x * blockDim.x + threadIdx.x;
    if (i < e) atomicAdd(&indeg[dst[i]], 1);
}

__global__ __launch_bounds__(256) void k_dinv(const int* __restrict__ indeg,
                                              float* __restrict__ dinv, int n) {
    int i = blockIdx.x * blockDim.x + threadIdx.x;
    if (i < n) dinv[i] = rsqrtf((float)(indeg[i] + 1));
}

__global__ __launch_bounds__(1024) void k_scan(const int* __restrict__ indeg,
                                               int* __restrict__ offsets, int n) {
    __shared__ int partial[1024];
    int tid = threadIdx.x;
    int chunk = (n + 1023) / 1024;
    int beg = tid * chunk;
    int end = beg + chunk; if (end > n) end = n; if (beg > n) beg = n;
    int sum = 0;
    for (int i = beg; i < end; ++i) sum += indeg[i];
    partial[tid] = sum;
    __syncthreads();
    for (int off = 1; off < 1024; off <<= 1) {
        int v = (tid >= off) ? partial[tid - off] : 0;
        __syncthreads();
        partial[tid] += v;
        __syncthreads();
    }
    int run = (tid > 0) ? partial[tid - 1] : 0;
    for (int i = beg; i < end; ++i) { offsets[i] = run; run += indeg[i]; }
    if (tid == 1023) offsets[n] = run;
}

__global__ __launch_bounds__(256) void k_scatter(const int* __restrict__ src,
                                                 const int* __restrict__ dst,
                                                 const float* __restrict__ dinv,
                                                 const int* __restrict__ offsets,
                                                 int* __restrict__ cursor,
                                                 int* __restrict__ csr_src,
                                                 float* __restrict__ csr_norm, int e) {
    int i = blockIdx.x * blockDim.x + threadIdx.x;
    if (i < e) {
        int d = dst[i], s = src[i];
        int pos = offsets[d] + atomicAdd(&cursor[d], 1);
        csr_src[pos] = s;
        csr_norm[pos] = dinv[s] * dinv[d];
    }
}

// ---------------- prep: x -> bf16 (padded), W -> W^T bf16 ----------------

__global__ __launch_bounds__(256) void k_cvt_x(const float* __restrict__ x,
                                               unsigned short* __restrict__ xb) {
    int i = blockIdx.x * blockDim.x + threadIdx.x;     // one thread = 4 elems
    int row = i >> 6;
    ushort4 o;
    if (row < N_NODES) {
        float4 v = *(const float4*)(x + (size_t)i * 4);
        o.x = f2bf(v.x); o.y = f2bf(v.y); o.z = f2bf(v.z); o.w = f2bf(v.w);
    } else {
        o.x = o.y = o.z = o.w = 0;
    }
    *(ushort4*)(xb + (size_t)i * 4) = o;
}

// W [K=256][N] f32 -> Wt [N][256] bf16
__global__ __launch_bounds__(256) void k_prep_w(const float* __restrict__ W,
                                                unsigned short* __restrict__ Wt, int N) {
    int i = blockIdx.x * blockDim.x + threadIdx.x;
    if (i < 256 * N) {
        int r = i / N, c = i - r * N;
        Wt[(size_t)c * 256 + r] = f2bf(W[i]);
    }
}

// ---------------- bf16 MFMA GEMM: C[MPAD][Ntot] = A[MPAD][256] @ Bt[Ntot][256]^T ----------------
// 128 x BN tile, BK=64, 4 waves (2x2), wave computes 64 x BN/2.
// LDS rows are 64 bf16 (128B = 8 x 16B chunks); chunk slot XOR-swizzled by (row&7).

template <int BN>
__global__ __launch_bounds__(256) void k_mfma_gemm(const unsigned short* __restrict__ A,
                                                   const unsigned short* __restrict__ Bt,
                                                   unsigned short* __restrict__ C,
                                                   int Ntot) {
    constexpr int K = 256, BK = 64;
    constexpr int NFR = BN / 32;            // 16-col frags per wave
    __shared__ char ldsA[128 * 128];
    __shared__ char ldsB[BN * 128];
    const int tid  = threadIdx.x;
    const int lane = tid & 63;
    const int wid  = tid >> 6;
    const int wr   = wid >> 1, wc = wid & 1;
    const int row0 = blockIdx.x * 128;
    const int col0 = blockIdx.y * BN;
    const int l15  = lane & 15, lhi = lane >> 4;

    f32x4 acc[4][NFR];
#pragma unroll
    for (int m = 0; m < 4; ++m)
#pragma unroll
        for (int n = 0; n < NFR; ++n) acc[m][n] = {0.f, 0.f, 0.f, 0.f};

    for (int k0 = 0; k0 < K; k0 += BK) {
        // stage A: 1024 x 16B chunks, source pre-swizzled so LDS dest is linear
#pragma unroll
        for (int j = 0; j < 4; ++j) {
            int ci = j * 256 + tid;
            int r = ci >> 3;
            int cb = (ci & 7) ^ (r & 7);
            const char* src = (const char*)(A + (size_t)(row0 + r) * K + k0) + cb * 16;
            __builtin_amdgcn_global_load_lds((const __attribute__((address_space(1))) void*)src,
                                             (__attribute__((address_space(3))) void*)(ldsA + ci * 16),
                                             16, 0, 0);
        }
        // stage Bt: BN*8 chunks
#pragma unroll
        for (int j = 0; j < BN / 32; ++j) {
            int ci = j * 256 + tid;
            int r = ci >> 3;
            int cb = (ci & 7) ^ (r & 7);
            const char* src = (const char*)(Bt + (size_t)(col0 + r) * K + k0) + cb * 16;
            __builtin_amdgcn_global_load_lds((const __attribute__((address_space(1))) void*)src,
                                             (__attribute__((address_space(3))) void*)(ldsB + ci * 16),
                                             16, 0, 0);
        }
        __syncthreads();
#pragma unroll
        for (int kk = 0; kk < 2; ++kk) {
            short8 af[4], bfr[NFR];
            int cb = kk * 4 + lhi;
#pragma unroll
            for (int m = 0; m < 4; ++m) {
                int r = wr * 64 + m * 16 + l15;
                af[m] = *(const short8*)(ldsA + r * 128 + ((cb ^ (r & 7)) << 4));
            }
#pragma unroll
            for (int n = 0; n < NFR; ++n) {
                int r = wc * (NFR * 16) + n * 16 + l15;
                bfr[n] = *(const short8*)(ldsB + r * 128 + ((cb ^ (r & 7)) << 4));
            }
#pragma unroll
            for (int m = 0; m < 4; ++m)
#pragma unroll
                for (int n = 0; n < NFR; ++n)
                    acc[m][n] = __builtin_amdgcn_mfma_f32_16x16x32_bf16(af[m], bfr[n],
                                                                        acc[m][n], 0, 0, 0);
        }
        __syncthreads();
    }
    // epilogue: C/D layout col=lane&15, row=(lane>>4)*4+q  [m89]
#pragma unroll
    for (int m = 0; m < 4; ++m)
#pragma unroll
        for (int n = 0; n < NFR; ++n) {
            int col = col0 + wc * (NFR * 16) + n * 16 + l15;
            int rbase = row0 + wr * 64 + m * 16 + lhi * 4;
#pragma unroll
            for (int q = 0; q < 4; ++q)
                C[(size_t)(rbase + q) * Ntot + col] = f2bf(acc[m][n][q]);
        }
}

// ---------------- aggregation: out = relu(Anorm * H + b), H bf16 ----------------
// one wave per node; VEC bf16 per lane (F = 64*VEC); OUT = unsigned short (bf16) or float

template <int VEC, typename OUT>
__global__ __launch_bounds__(256) void k_aggregate(const unsigned short* __restrict__ H,
                                                   const int* __restrict__ offsets,
                                                   const int* __restrict__ csr_src,
                                                   const float* __restrict__ csr_norm,
                                                   const float* __restrict__ dinv,
                                                   const float* __restrict__ bias,
                                                   OUT* __restrict__ out, int n) {
    constexpr int F = 64 * VEC;
    const int wid = (blockIdx.x * blockDim.x + threadIdx.x) >> 6;
    const int lane = threadIdx.x & 63;
    if (wid >= n) return;

    float acc[VEC];
#pragma unroll
    for (int v = 0; v < VEC; ++v) acc[v] = 0.f;

    const int beg = offsets[wid], end = offsets[wid + 1];
    int e = beg;
    for (; e + 3 < end; e += 4) {
        int s0 = csr_src[e], s1 = csr_src[e + 1], s2 = csr_src[e + 2], s3 = csr_src[e + 3];
        float n0 = csr_norm[e], n1 = csr_norm[e + 1], n2 = csr_norm[e + 2], n3 = csr_norm[e + 3];
        if (VEC == 4) {
            ushort4 v0 = *(const ushort4*)(H + (size_t)s0 * F + (lane << 2));
            ushort4 v1 = *(const ushort4*)(H + (size_t)s1 * F + (lane << 2));
            ushort4 v2 = *(const ushort4*)(H + (size_t)s2 * F + (lane << 2));
            ushort4 v3 = *(const ushort4*)(H + (size_t)s3 * F + (lane << 2));
            acc[0] += bf2f(v0.x) * n0 + bf2f(v1.x) * n1 + bf2f(v2.x) * n2 + bf2f(v3.x) * n3;
            acc[1] += bf2f(v0.y) * n0 + bf2f(v1.y) * n1 + bf2f(v2.y) * n2 + bf2f(v3.y) * n3;
            acc[2] += bf2f(v0.z) * n0 + bf2f(v1.z) * n1 + bf2f(v2.z) * n2 + bf2f(v3.z) * n3;
            acc[3] += bf2f(v0.w) * n0 + bf2f(v1.w) * n1 + bf2f(v2.w) * n2 + bf2f(v3.w) * n3;
        } else {
            acc[0] += bf2f(H[(size_t)s0 * F + lane]) * n0 + bf2f(H[(size_t)s1 * F + lane]) * n1
                    + bf2f(H[(size_t)s2 * F + lane]) * n2 + bf2f(H[(size_t)s3 * F + lane]) * n3;
        }
    }
    for (; e < end; ++e) {
        int s = csr_src[e];
        float nrm = csr_norm[e];
        if (VEC == 4) {
            ushort4 v = *(const ushort4*)(H + (size_t)s * F + (lane << 2));
            acc[0] += bf2f(v.x) * nrm; acc[1] += bf2f(v.y) * nrm;
            acc[2] += bf2f(v.z) * nrm; acc[3] += bf2f(v.w) * nrm;
        } else {
            acc[0] += bf2f(H[(size_t)s * F + lane]) * nrm;
        }
    }
    float dv = dinv[wid];
    float sw = dv * dv;
    if (VEC == 4) {
        ushort4 v = *(const ushort4*)(H + (size_t)wid * F + (lane << 2));
        float4 b = *(const float4*)(bias + (lane << 2));
        float r0 = fmaxf(acc[0] + bf2f(v.x) * sw + b.x, 0.f);
        float r1 = fmaxf(acc[1] + bf2f(v.y) * sw + b.y, 0.f);
        float r2 = fmaxf(acc[2] + bf2f(v.z) * sw + b.z, 0.f);
        float r3 = fmaxf(acc[3] + bf2f(v.w) * sw + b.w, 0.f);
        if constexpr (sizeof(OUT) == 2) {
            ushort4 o; o.x = f2bf(r0); o.y = f2bf(r1); o.z = f2bf(r2); o.w = f2bf(r3);
            *(ushort4*)((unsigned short*)out + (size_t)wid * F + (lane << 2)) = o;
        } else {
            *(float4*)((float*)out + (size_t)wid * F + (lane << 2)) = make_float4(r0, r1, r2, r3);
        }
    } else {
        float r = fmaxf(acc[0] + bf2f(H[(size_t)wid * F + lane]) * sw + bias[lane], 0.f);
        if constexpr (sizeof(OUT) == 2)
            ((unsigned short*)out)[(size_t)wid * F + lane] = f2bf(r);
        else
            ((float*)out)[(size_t)wid * F + lane] = r;
    }
}

// ---------------- launch ----------------

extern "C" void kernel_launch(void* const* d_in, const int* in_sizes, int n_in,
                              void* d_out, int out_size, void* d_ws, size_t ws_size,
                              hipStream_t stream) {
    const float* x      = (const float*)d_in[0];
    const float* W_enc  = (const float*)d_in[1];
    const float* b_enc  = (const float*)d_in[2];
    const float* W_conv = (const float*)d_in[3];
    const float* b_conv = (const float*)d_in[4];
    const float* W_dec  = (const float*)d_in[5];
    const float* b_dec  = (const float*)d_in[6];
    const int*   ei     = (const int*)d_in[7];

    const int N = N_NODES;
    const int E = N_EDGES;
    const int* src = ei;
    const int* dst = ei + E;

    size_t off = 0;
    auto carve = [&](size_t bytes) -> void* {
        void* p = (char*)d_ws + off;
        off = (off + bytes + 255) & ~(size_t)255;
        return p;
    };
    unsigned short* Xb      = (unsigned short*)carve((size_t)MPAD * 256 * 2);
    unsigned short* Hb      = (unsigned short*)carve((size_t)MPAD * 256 * 2);
    unsigned short* Wt_enc  = (unsigned short*)carve((size_t)256 * 256 * 2);
    unsigned short* Wt_conv = (unsigned short*)carve((size_t)256 * 256 * 2);
    unsigned short* Wt_dec  = (unsigned short*)carve((size_t)64 * 256 * 2);
    int*            indeg   = (int*)carve((size_t)N * sizeof(int));
    int*            cursor  = (int*)carve((size_t)N * sizeof(int));
    float*          dinv    = (float*)carve((size_t)N * sizeof(float));
    int*            offsets = (int*)carve((size_t)(N + 1) * sizeof(int));
    int*            csr_src = (int*)carve((size_t)E * sizeof(int));
    float*          csr_nrm = (float*)carve((size_t)E * sizeof(float));
    (void)ws_size;

    // --- prep + CSR build ---
    k_cvt_x<<<MPAD / 4, 256, 0, stream>>>(x, Xb);
    k_prep_w<<<(256 * 256 + 255) / 256, 256, 0, stream>>>(W_enc, Wt_enc, 256);
    k_prep_w<<<(256 * 256 + 255) / 256, 256, 0, stream>>>(W_conv, Wt_conv, 256);
    k_prep_w<<<(256 * 64 + 255) / 256, 256, 0, stream>>>(W_dec, Wt_dec, 64);
    k_init<<<(N + 255) / 256, 256, 0, stream>>>(indeg, cursor, N);
    k_indeg<<<(E + 255) / 256, 256, 0, stream>>>(dst, indeg, E);
    k_dinv<<<(N + 255) / 256, 256, 0, stream>>>(indeg, dinv, N);
    k_scan<<<1, 1024, 0, stream>>>(indeg, offsets, N);
    k_scatter<<<(E + 255) / 256, 256, 0, stream>>>(src, dst, dinv, offsets, cursor,
                                                   csr_src, csr_nrm, E);

    dim3 gconv(MPAD / 128, 2);   // 782 x 2, BN=128
    dim3 gdec(MPAD / 128, 1);    // BN=64
    const int agg_blocks = (N * 64 + 255) / 256;

    // --- encoder ---
    k_mfma_gemm<128><<<gconv, 256, 0, stream>>>(Xb, Wt_enc, Hb, 256);
    k_aggregate<4, unsigned short><<<agg_blocks, 256, 0, stream>>>(Hb, offsets, csr_src,
                                                                   csr_nrm, dinv, b_enc, Xb, N);
    // --- 4 conv layers ---
    for (int l = 0; l < 4; ++l) {
        k_mfma_gemm<128><<<gconv, 256, 0, stream>>>(Xb, Wt_conv, Hb, 256);
        k_aggregate<4, unsigned short><<<agg_blocks, 256, 0, stream>>>(Hb, offsets, csr_src,
                                                                       csr_nrm, dinv, b_conv, Xb, N);
    }
    // --- decoder ---
    k_mfma_gemm<64><<<gdec, 256, 0, stream>>>(Xb, Wt_dec, Hb, 64);
    k_aggregate<1, float><<<agg_blocks, 256, 0, stream>>>(Hb, offsets, csr_src,
                                                          csr_nrm, dinv, b_dec,
                                                          (float*)d_out, N);
}

// Round 4
// 1003.438 us; speedup vs baseline: 2.6180x; 1.1877x over previous
//
#include <hip/hip_runtime.h>

#define N_NODES 100000
#define N_EDGES 1600000
#define MPAD    100096   // 782 * 128
#define NB_SCAN ((N_NODES + 255) / 256)   // 391

using short8 = __attribute__((ext_vector_type(8))) short;
using f32x4  = __attribute__((ext_vector_type(4))) float;

__device__ inline unsigned short f2bf(float f) {
    unsigned u = __float_as_uint(f);
    unsigned r = (u + 0x7fffu + ((u >> 16) & 1u)) >> 16;  // RNE
    return (unsigned short)r;
}
__device__ inline float bf2f(unsigned short h) {
    return __uint_as_float(((unsigned)h) << 16);
}

// ---------------- CSR build ----------------

__global__ __launch_bounds__(256) void k_init(int* __restrict__ indeg,
                                              int* __restrict__ cursor, int n) {
    int i = blockIdx.x * blockDim.x + threadIdx.x;
    if (i < n) { indeg[i] = 0; cursor[i] = 0; }
}

__global__ __launch_bounds__(256) void k_indeg(const int* __restrict__ dst,
                                               int* __restrict__ indeg, int e) {
    int i = blockIdx.x * blockDim.x + threadIdx.x;
    if (i < e) atomicAdd(&indeg[dst[i]], 1);
}

// two-level scan: partial sums -> top scan -> local scan (+ fused dinv)
__global__ __launch_bounds__(256) void k_scan_blocks(const int* __restrict__ indeg,
                                                     int* __restrict__ blksum, int n) {
    int i = blockIdx.x * 256 + threadIdx.x;
    int v = (i < n) ? indeg[i] : 0;
#pragma unroll
    for (int o = 32; o > 0; o >>= 1) v += __shfl_down(v, o, 64);
    __shared__ int ws[4];
    if ((threadIdx.x & 63) == 0) ws[threadIdx.x >> 6] = v;
    __syncthreads();
    if (threadIdx.x == 0) blksum[blockIdx.x] = ws[0] + ws[1] + ws[2] + ws[3];
}

__global__ __launch_bounds__(512) void k_scan_top(const int* __restrict__ blksum,
                                                  int* __restrict__ blkpref,
                                                  int* __restrict__ offsets, int nb, int n) {
    __shared__ int s[512];
    int t = threadIdx.x;
    int v = (t < nb) ? blksum[t] : 0;
    s[t] = v;
    __syncthreads();
    for (int o = 1; o < 512; o <<= 1) {
        int u = (t >= o) ? s[t - o] : 0;
        __syncthreads();
        s[t] += u;
        __syncthreads();
    }
    if (t < nb) blkpref[t] = (t == 0) ? 0 : s[t - 1];
    if (t == nb - 1) offsets[n] = s[t];
}

__global__ __launch_bounds__(256) void k_scan_final(const int* __restrict__ indeg,
                                                    const int* __restrict__ blkpref,
                                                    int* __restrict__ offsets,
                                                    float* __restrict__ dinv, int n) {
    __shared__ int s[256];
    int t = threadIdx.x;
    int i = blockIdx.x * 256 + t;
    int v = (i < n) ? indeg[i] : 0;
    s[t] = v;
    __syncthreads();
    for (int o = 1; o < 256; o <<= 1) {
        int u = (t >= o) ? s[t - o] : 0;
        __syncthreads();
        s[t] += u;
        __syncthreads();
    }
    if (i < n) {
        offsets[i] = blkpref[blockIdx.x] + s[t] - v;   // exclusive prefix
        dinv[i] = rsqrtf((float)(v + 1));              // +1 self-loop
    }
}

__global__ __launch_bounds__(256) void k_scatter(const int* __restrict__ src,
                                                 const int* __restrict__ dst,
                                                 const float* __restrict__ dinv,
                                                 const int* __restrict__ offsets,
                                                 int* __restrict__ cursor,
                                                 int* __restrict__ csr_src,
                                                 float* __restrict__ csr_norm, int e) {
    int i = blockIdx.x * blockDim.x + threadIdx.x;
    if (i < e) {
        int d = dst[i], s = src[i];
        int pos = offsets[d] + atomicAdd(&cursor[d], 1);
        csr_src[pos] = s;
        csr_norm[pos] = dinv[s] * dinv[d];
    }
}

// ---------------- prep: x -> bf16 (padded), W -> W^T bf16 ----------------

__global__ __launch_bounds__(256) void k_cvt_x(const float* __restrict__ x,
                                               unsigned short* __restrict__ xb) {
    int i = blockIdx.x * blockDim.x + threadIdx.x;     // one thread = 4 elems
    int row = i >> 6;
    ushort4 o;
    if (row < N_NODES) {
        float4 v = *(const float4*)(x + (size_t)i * 4);
        o.x = f2bf(v.x); o.y = f2bf(v.y); o.z = f2bf(v.z); o.w = f2bf(v.w);
    } else {
        o.x = o.y = o.z = o.w = 0;
    }
    *(ushort4*)(xb + (size_t)i * 4) = o;
}

// W [K=256][N] f32 -> Wt [N][256] bf16
__global__ __launch_bounds__(256) void k_prep_w(const float* __restrict__ W,
                                                unsigned short* __restrict__ Wt, int N) {
    int i = blockIdx.x * blockDim.x + threadIdx.x;
    if (i < 256 * N) {
        int r = i / N, c = i - r * N;
        Wt[(size_t)c * 256 + r] = f2bf(W[i]);
    }
}

// ---------------- bf16 MFMA GEMM: C[MPAD][Ntot] = A[MPAD][256] @ Bt[Ntot][256]^T ----------------
// 128 x BN tile, BK=64, 4 waves (2x2), wave computes 64 x BN/2.
// LDS rows are 64 bf16 (128B = 8 x 16B chunks); chunk slot XOR-swizzled by (row&7).

template <int BN>
__global__ __launch_bounds__(256) void k_mfma_gemm(const unsigned short* __restrict__ A,
                                                   const unsigned short* __restrict__ Bt,
                                                   unsigned short* __restrict__ C,
                                                   int Ntot) {
    constexpr int K = 256, BK = 64;
    constexpr int NFR = BN / 32;            // 16-col frags per wave
    __shared__ char ldsA[128 * 128];
    __shared__ char ldsB[BN * 128];
    const int tid  = threadIdx.x;
    const int lane = tid & 63;
    const int wid  = tid >> 6;
    const int wr   = wid >> 1, wc = wid & 1;
    const int row0 = blockIdx.x * 128;
    const int col0 = blockIdx.y * BN;
    const int l15  = lane & 15, lhi = lane >> 4;

    f32x4 acc[4][NFR];
#pragma unroll
    for (int m = 0; m < 4; ++m)
#pragma unroll
        for (int n = 0; n < NFR; ++n) acc[m][n] = {0.f, 0.f, 0.f, 0.f};

    for (int k0 = 0; k0 < K; k0 += BK) {
        // stage A: 1024 x 16B chunks, source pre-swizzled so LDS dest is linear
#pragma unroll
        for (int j = 0; j < 4; ++j) {
            int ci = j * 256 + tid;
            int r = ci >> 3;
            int cb = (ci & 7) ^ (r & 7);
            const char* src = (const char*)(A + (size_t)(row0 + r) * K + k0) + cb * 16;
            __builtin_amdgcn_global_load_lds((const __attribute__((address_space(1))) void*)src,
                                             (__attribute__((address_space(3))) void*)(ldsA + ci * 16),
                                             16, 0, 0);
        }
        // stage Bt: BN*8 chunks
#pragma unroll
        for (int j = 0; j < BN / 32; ++j) {
            int ci = j * 256 + tid;
            int r = ci >> 3;
            int cb = (ci & 7) ^ (r & 7);
            const char* src = (const char*)(Bt + (size_t)(col0 + r) * K + k0) + cb * 16;
            __builtin_amdgcn_global_load_lds((const __attribute__((address_space(1))) void*)src,
                                             (__attribute__((address_space(3))) void*)(ldsB + ci * 16),
                                             16, 0, 0);
        }
        __syncthreads();
#pragma unroll
        for (int kk = 0; kk < 2; ++kk) {
            short8 af[4], bfr[NFR];
            int cb = kk * 4 + lhi;
#pragma unroll
            for (int m = 0; m < 4; ++m) {
                int r = wr * 64 + m * 16 + l15;
                af[m] = *(const short8*)(ldsA + r * 128 + ((cb ^ (r & 7)) << 4));
            }
#pragma unroll
            for (int n = 0; n < NFR; ++n) {
                int r = wc * (NFR * 16) + n * 16 + l15;
                bfr[n] = *(const short8*)(ldsB + r * 128 + ((cb ^ (r & 7)) << 4));
            }
#pragma unroll
            for (int m = 0; m < 4; ++m)
#pragma unroll
                for (int n = 0; n < NFR; ++n)
                    acc[m][n] = __builtin_amdgcn_mfma_f32_16x16x32_bf16(af[m], bfr[n],
                                                                        acc[m][n], 0, 0, 0);
        }
        __syncthreads();
    }
    // epilogue: C/D layout col=lane&15, row=(lane>>4)*4+q  [m89]
#pragma unroll
    for (int m = 0; m < 4; ++m)
#pragma unroll
        for (int n = 0; n < NFR; ++n) {
            int col = col0 + wc * (NFR * 16) + n * 16 + l15;
            int rbase = row0 + wr * 64 + m * 16 + lhi * 4;
#pragma unroll
            for (int q = 0; q < 4; ++q)
                C[(size_t)(rbase + q) * Ntot + col] = f2bf(acc[m][n][q]);
        }
}

// ---------------- aggregation: out = relu(Anorm * H + b), H bf16 ----------------
// one wave per node; VEC bf16 per lane (F = 64*VEC); OUT = unsigned short (bf16) or float

template <int VEC, typename OUT>
__global__ __launch_bounds__(256) void k_aggregate(const unsigned short* __restrict__ H,
                                                   const int* __restrict__ offsets,
                                                   const int* __restrict__ csr_src,
                                                   const float* __restrict__ csr_norm,
                                                   const float* __restrict__ dinv,
                                                   const float* __restrict__ bias,
                                                   OUT* __restrict__ out, int n) {
    constexpr int F = 64 * VEC;
    const int wid = (blockIdx.x * blockDim.x + threadIdx.x) >> 6;
    const int lane = threadIdx.x & 63;
    if (wid >= n) return;

    float acc[VEC];
#pragma unroll
    for (int v = 0; v < VEC; ++v) acc[v] = 0.f;

    const int beg = offsets[wid], end = offsets[wid + 1];
    int e = beg;
    for (; e + 3 < end; e += 4) {
        int s0 = csr_src[e], s1 = csr_src[e + 1], s2 = csr_src[e + 2], s3 = csr_src[e + 3];
        float n0 = csr_norm[e], n1 = csr_norm[e + 1], n2 = csr_norm[e + 2], n3 = csr_norm[e + 3];
        if (VEC == 4) {
            ushort4 v0 = *(const ushort4*)(H + (size_t)s0 * F + (lane << 2));
            ushort4 v1 = *(const ushort4*)(H + (size_t)s1 * F + (lane << 2));
            ushort4 v2 = *(const ushort4*)(H + (size_t)s2 * F + (lane << 2));
            ushort4 v3 = *(const ushort4*)(H + (size_t)s3 * F + (lane << 2));
            acc[0] += bf2f(v0.x) * n0 + bf2f(v1.x) * n1 + bf2f(v2.x) * n2 + bf2f(v3.x) * n3;
            acc[1] += bf2f(v0.y) * n0 + bf2f(v1.y) * n1 + bf2f(v2.y) * n2 + bf2f(v3.y) * n3;
            acc[2] += bf2f(v0.z) * n0 + bf2f(v1.z) * n1 + bf2f(v2.z) * n2 + bf2f(v3.z) * n3;
            acc[3] += bf2f(v0.w) * n0 + bf2f(v1.w) * n1 + bf2f(v2.w) * n2 + bf2f(v3.w) * n3;
        } else {
            acc[0] += bf2f(H[(size_t)s0 * F + lane]) * n0 + bf2f(H[(size_t)s1 * F + lane]) * n1
                    + bf2f(H[(size_t)s2 * F + lane]) * n2 + bf2f(H[(size_t)s3 * F + lane]) * n3;
        }
    }
    for (; e < end; ++e) {
        int s = csr_src[e];
        float nrm = csr_norm[e];
        if (VEC == 4) {
            ushort4 v = *(const ushort4*)(H + (size_t)s * F + (lane << 2));
            acc[0] += bf2f(v.x) * nrm; acc[1] += bf2f(v.y) * nrm;
            acc[2] += bf2f(v.z) * nrm; acc[3] += bf2f(v.w) * nrm;
        } else {
            acc[0] += bf2f(H[(size_t)s * F + lane]) * nrm;
        }
    }
    float dv = dinv[wid];
    float sw = dv * dv;
    if (VEC == 4) {
        ushort4 v = *(const ushort4*)(H + (size_t)wid * F + (lane << 2));
        float4 b = *(const float4*)(bias + (lane << 2));
        float r0 = fmaxf(acc[0] + bf2f(v.x) * sw + b.x, 0.f);
        float r1 = fmaxf(acc[1] + bf2f(v.y) * sw + b.y, 0.f);
        float r2 = fmaxf(acc[2] + bf2f(v.z) * sw + b.z, 0.f);
        float r3 = fmaxf(acc[3] + bf2f(v.w) * sw + b.w, 0.f);
        if constexpr (sizeof(OUT) == 2) {
            ushort4 o; o.x = f2bf(r0); o.y = f2bf(r1); o.z = f2bf(r2); o.w = f2bf(r3);
            *(ushort4*)((unsigned short*)out + (size_t)wid * F + (lane << 2)) = o;
        } else {
            *(float4*)((float*)out + (size_t)wid * F + (lane << 2)) = make_float4(r0, r1, r2, r3);
        }
    } else {
        float r = fmaxf(acc[0] + bf2f(H[(size_t)wid * F + lane]) * sw + bias[lane], 0.f);
        if constexpr (sizeof(OUT) == 2)
            ((unsigned short*)out)[(size_t)wid * F + lane] = f2bf(r);
        else
            ((float*)out)[(size_t)wid * F + lane] = r;
    }
}

// ---------------- launch ----------------

extern "C" void kernel_launch(void* const* d_in, const int* in_sizes, int n_in,
                              void* d_out, int out_size, void* d_ws, size_t ws_size,
                              hipStream_t stream) {
    const float* x      = (const float*)d_in[0];
    const float* W_enc  = (const float*)d_in[1];
    const float* b_enc  = (const float*)d_in[2];
    const float* W_conv = (const float*)d_in[3];
    const float* b_conv = (const float*)d_in[4];
    const float* W_dec  = (const float*)d_in[5];
    const float* b_dec  = (const float*)d_in[6];
    const int*   ei     = (const int*)d_in[7];

    const int N = N_NODES;
    const int E = N_EDGES;
    const int* src = ei;
    const int* dst = ei + E;

    size_t off = 0;
    auto carve = [&](size_t bytes) -> void* {
        void* p = (char*)d_ws + off;
        off = (off + bytes + 255) & ~(size_t)255;
        return p;
    };
    unsigned short* Xb      = (unsigned short*)carve((size_t)MPAD * 256 * 2);
    unsigned short* Hb      = (unsigned short*)carve((size_t)MPAD * 256 * 2);
    unsigned short* Wt_enc  = (unsigned short*)carve((size_t)256 * 256 * 2);
    unsigned short* Wt_conv = (unsigned short*)carve((size_t)256 * 256 * 2);
    unsigned short* Wt_dec  = (unsigned short*)carve((size_t)64 * 256 * 2);
    int*            indeg   = (int*)carve((size_t)N * sizeof(int));
    int*            cursor  = (int*)carve((size_t)N * sizeof(int));
    float*          dinv    = (float*)carve((size_t)N * sizeof(float));
    int*            offsets = (int*)carve((size_t)(N + 1) * sizeof(int));
    int*            csr_src = (int*)carve((size_t)E * sizeof(int));
    float*          csr_nrm = (float*)carve((size_t)E * sizeof(float));
    int*            blksum  = (int*)carve((size_t)NB_SCAN * sizeof(int));
    int*            blkpref = (int*)carve((size_t)NB_SCAN * sizeof(int));
    (void)ws_size;

    // --- prep + CSR build ---
    k_cvt_x<<<MPAD / 4, 256, 0, stream>>>(x, Xb);
    k_prep_w<<<(256 * 256 + 255) / 256, 256, 0, stream>>>(W_enc, Wt_enc, 256);
    k_prep_w<<<(256 * 256 + 255) / 256, 256, 0, stream>>>(W_conv, Wt_conv, 256);
    k_prep_w<<<(256 * 64 + 255) / 256, 256, 0, stream>>>(W_dec, Wt_dec, 64);
    k_init<<<(N + 255) / 256, 256, 0, stream>>>(indeg, cursor, N);
    k_indeg<<<(E + 255) / 256, 256, 0, stream>>>(dst, indeg, E);
    k_scan_blocks<<<NB_SCAN, 256, 0, stream>>>(indeg, blksum, N);
    k_scan_top<<<1, 512, 0, stream>>>(blksum, blkpref, offsets, NB_SCAN, N);
    k_scan_final<<<NB_SCAN, 256, 0, stream>>>(indeg, blkpref, offsets, dinv, N);
    k_scatter<<<(E + 255) / 256, 256, 0, stream>>>(src, dst, dinv, offsets, cursor,
                                                   csr_src, csr_nrm, E);

    dim3 gconv(MPAD / 128, 2);   // 782 x 2, BN=128
    dim3 gdec(MPAD / 128, 1);    // BN=64
    const int agg_blocks = (N * 64 + 255) / 256;

    // --- encoder ---
    k_mfma_gemm<128><<<gconv, 256, 0, stream>>>(Xb, Wt_enc, Hb, 256);
    k_aggregate<4, unsigned short><<<agg_blocks, 256, 0, stream>>>(Hb, offsets, csr_src,
                                                                   csr_nrm, dinv, b_enc, Xb, N);
    // --- 4 conv layers ---
    for (int l = 0; l < 4; ++l) {
        k_mfma_gemm<128><<<gconv, 256, 0, stream>>>(Xb, Wt_conv, Hb, 256);
        k_aggregate<4, unsigned short><<<agg_blocks, 256, 0, stream>>>(Hb, offsets, csr_src,
                                                                       csr_nrm, dinv, b_conv, Xb, N);
    }
    // --- decoder ---
    k_mfma_gemm<64><<<gdec, 256, 0, stream>>>(Xb, Wt_dec, Hb, 64);
    k_aggregate<1, float><<<agg_blocks, 256, 0, stream>>>(Hb, offsets, csr_src,
                                                          csr_nrm, dinv, b_dec,
                                                          (float*)d_out, N);
}